// Round 17
// baseline (250.550 us; speedup 1.0000x reference)
//
#include <hip/hip_runtime.h>
#include <hip/hip_bf16.h>

#define B_ 64
#define S_ 512
#define E_ 1024
#define P_ 200
#define K_ 10
#define C_ 3

#define BM 128
#define BN 160                 // 16 protos
#define BKS 64                 // K elements per LDS stage
#define NSTAGE (E_ / BKS)      // 16
#define NROWS_A (B_ * S_)      // 32768
#define NROWS_B (P_ * K_)      // 2000
#define NMT 256                // m-tiles (32768/128)
#define NNT 13                 // n-tiles (2080/160)
#define NBPAD (NNT * BN)       // 2080
#define NROWS_P (NROWS_A + NBPAD)  // 34848

typedef __attribute__((ext_vector_type(8))) short short8;
typedef __attribute__((ext_vector_type(4))) float f32x4;

__device__ __forceinline__ float bf2f(unsigned short u) {
    unsigned int x = ((unsigned int)u) << 16;
    return __uint_as_float(x);
}
__device__ __forceinline__ unsigned short f2bf(float f) {
    __hip_bfloat16 h = __float2bfloat16(f);
    unsigned short u;
    __builtin_memcpy(&u, &h, 2);
    return u;
}

// Read-side swizzle: row-major [row][64] bf16 (row stride 128 B); logical 16B
// chunk kbyte>>4 lives at physical slot (kbyte>>4)^(row&7). Involution with the
// pre-swizzled staging SOURCE column (rule #21 / m173). Verified conflict-free
// for the 16x16 fragment read pattern (r4/r5/r12: K-loop conflicts = 0).
__device__ __forceinline__ int swz(int row, int kbyte) {
    return (row * (BKS * 2) + kbyte) ^ ((row & 7) << 4);
}

#define GLDS16(gsrc, ldst)                                                              \
    __builtin_amdgcn_global_load_lds((const __attribute__((address_space(1))) unsigned int*)(gsrc), \
                                     (__attribute__((address_space(3))) unsigned int*)(ldst), 16, 0, 0)

// ---------------------------------------------------------------------------
// Pass 1: f32 -> bf16 for emb (rows 0..32767), proto (rows 32768..34767),
// zero pad (34768..34847); per-row |.|^2 of the rounded values.
__global__ __launch_bounds__(256) void preconvert(const float* __restrict__ emb,
                                                  const float* __restrict__ proto,
                                                  unsigned short* __restrict__ bf,
                                                  float* __restrict__ xy2) {
    const int row  = blockIdx.x * 4 + (threadIdx.x >> 6);
    const int lane = threadIdx.x & 63;
    unsigned short* dst = bf + (size_t)row * E_;

    if (row >= NROWS_A + NROWS_B) {
        ushort4 z = {0, 0, 0, 0};
#pragma unroll
        for (int p = 0; p < 4; ++p) *(ushort4*)(dst + p * 256 + lane * 4) = z;
        if (lane == 0) xy2[row] = 0.f;
        return;
    }
    const float* src = (row < NROWS_A) ? emb + (size_t)row * E_
                                       : proto + (size_t)(row - NROWS_A) * E_;
    float s = 0.f;
#pragma unroll
    for (int p = 0; p < 4; ++p) {
        float4 v = *(const float4*)(src + p * 256 + lane * 4);
        ushort4 h = { f2bf(v.x), f2bf(v.y), f2bf(v.z), f2bf(v.w) };
        float a = bf2f(h.x), b = bf2f(h.y), c = bf2f(h.z), d = bf2f(h.w);
        s += a * a + b * b + c * c + d * d;
        *(ushort4*)(dst + p * 256 + lane * 4) = h;
    }
#pragma unroll
    for (int off = 32; off > 0; off >>= 1) s += __shfl_xor(s, off);
    if (lane == 0) xy2[row] = s;
}

// ---------------------------------------------------------------------------
// Pass 2: bf16 GEMM, BM=128 x BN=160, 256 threads / 4 waves as 2m x 2n.
// Per-wave geometry IDENTICAL to r12 (64x80 = 4x5 frags, 0.45 reads/MFMA,
// conflict-free swizzle) -- only the block is halved: LDS 73.4 KB ->
// 2 blocks/CU. Clean co-residency test: r8/r15's occupancy probes were
// confounded by K-loop bank conflicts; this one has none.
__global__ __launch_bounds__(256) void dist_gemm_bf(const unsigned short* __restrict__ Abf,
                                                    const unsigned short* __restrict__ Bbf,
                                                    const float* __restrict__ x2g,
                                                    const float* __restrict__ y2g,
                                                    float* __restrict__ dist,
                                                    float* __restrict__ ws_min) {
    __shared__ __align__(16) unsigned char smem[73728]; // As 2x16KB | Bs 2x20KB ; CH aliases
    __shared__ float red[4][80];                        // 1.25 KB (total ~75 KB -> 2 blocks/CU)

    unsigned short* AsBase = (unsigned short*)smem;                       // [2][BM*BKS]
    unsigned short* BsBase = (unsigned short*)(smem + 2 * BM * BKS * 2);  // [2][BN*BKS]
    float* Ch = (float*)smem;                                             // [2][16][162] = 20.7 KB

    const int tid  = threadIdx.x;
    const int lane = tid & 63;
    const int wv   = tid >> 6;      // 0..3
    const int wm   = wv >> 1;       // 0..1  (64-row band)
    const int wn   = wv & 1;        // 0..1  (80-col band)
    const int l15  = lane & 15;
    const int lh   = lane >> 4;

    // XCD-aware swizzle (3328 % 8 == 0): each XCD gets 32 consecutive m-tiles
    // x all 13 n-tiles.
    const int id = blockIdx.x;
    const int sw = (id & 7) * (3328 / 8) + (id >> 3);
    const int nt = sw % NNT;
    const int mt = sw / NNT;

    // Staging. A: 1024 chunks (128 rows x 8), 4/thread. B: 1280 chunks
    // (160 rows x 8), 5/thread (exact). LDS dest linear; swizzle via
    // inverse-permuted SOURCE column c^(r&7).
    const unsigned short* aSrc[4];
    unsigned lOffA[4];
#pragma unroll
    for (int i = 0; i < 4; ++i) {
        int idx = i * 256 + tid;
        int r = idx >> 3, c = idx & 7;
        aSrc[i]  = Abf + (size_t)(mt * BM + r) * E_ + (c ^ (r & 7)) * 8;
        lOffA[i] = (unsigned)(i * 256 + wv * 64) * 8;
    }
    const unsigned short* bSrc[5];
    unsigned lOffB[5];
#pragma unroll
    for (int i = 0; i < 5; ++i) {
        int idx = i * 256 + tid;
        int r = idx >> 3, c = idx & 7;
        bSrc[i]  = Bbf + (size_t)(nt * BN + r) * E_ + (c ^ (r & 7)) * 8;
        lOffB[i] = (unsigned)(i * 256 + wv * 64) * 8;
    }

    f32x4 acc[4][5];
#pragma unroll
    for (int i = 0; i < 4; ++i)
#pragma unroll
        for (int j = 0; j < 5; ++j) acc[i][j] = (f32x4){0.f, 0.f, 0.f, 0.f};

#define ISSUE(tt, bb)                                                          \
    do {                                                                       \
        const size_t ko_ = (size_t)(tt) * BKS;                                 \
        unsigned short* Asb_ = AsBase + (bb) * (BM * BKS);                     \
        unsigned short* Bsb_ = BsBase + (bb) * (BN * BKS);                     \
        _Pragma("unroll")                                                      \
        for (int i_ = 0; i_ < 4; ++i_) GLDS16(aSrc[i_] + ko_, Asb_ + lOffA[i_]); \
        _Pragma("unroll")                                                      \
        for (int i_ = 0; i_ < 5; ++i_) GLDS16(bSrc[i_] + ko_, Bsb_ + lOffB[i_]); \
    } while (0)

#define COMPUTE(bb)                                                            \
    do {                                                                       \
        const char* Ab_ = (const char*)(AsBase + (bb) * (BM * BKS));           \
        const char* Bb_ = (const char*)(BsBase + (bb) * (BN * BKS));           \
        _Pragma("unroll")                                                      \
        for (int kk = 0; kk < 2; ++kk) {                                       \
            const int kbyte = kk * 64 + lh * 16;                               \
            short8 af[4];                                                      \
            _Pragma("unroll")                                                  \
            for (int mf = 0; mf < 4; ++mf)                                     \
                af[mf] = *(const short8*)(Ab_ + swz(wm * 64 + mf * 16 + l15, kbyte)); \
            short8 bfr[5];                                                     \
            _Pragma("unroll")                                                  \
            for (int nf = 0; nf < 5; ++nf)                                     \
                bfr[nf] = *(const short8*)(Bb_ + swz(wn * 80 + nf * 16 + l15, kbyte)); \
            _Pragma("unroll")                                                  \
            for (int mf = 0; mf < 4; ++mf)                                     \
                _Pragma("unroll")                                              \
                for (int nf = 0; nf < 5; ++nf)                                 \
                    acc[mf][nf] = __builtin_amdgcn_mfma_f32_16x16x32_bf16(     \
                        af[mf], bfr[nf], acc[mf][nf], 0, 0, 0);                \
        }                                                                      \
    } while (0)

    ISSUE(0, 0);
    __syncthreads();

    int buf = 0;
    for (int t = 0; t < NSTAGE; ++t) {
        if (t + 1 < NSTAGE) ISSUE(t + 1, buf ^ 1);
        COMPUTE(buf);
        __syncthreads();
        buf ^= 1;
    }
#undef ISSUE
#undef COMPUTE

    // ----- Epilogue (r12's CH-staged coalesced form, 2 slabs) -----
    // C/D layout: col = lane&15, row = (lane>>4)*4 + reg.
    const int b  = mt >> 2;            // BM=128: four m-tiles per b
    const int s0 = (mt & 3) * 128;

    float y2v[5];
#pragma unroll
    for (int nf = 0; nf < 5; ++nf) y2v[nf] = y2g[nt * BN + wn * 80 + nf * 16 + l15];

    float mloc[5];
#pragma unroll
    for (int nf = 0; nf < 5; ++nf) mloc[nf] = 3.4e38f;

#define CH(slab, row, col) Ch[(((slab) * 16) + (row)) * 162 + (col)]

#pragma unroll
    for (int mf = 0; mf < 4; ++mf) {   // per mf: 2 slabs (wm) x 16 rows x 160 cols
#pragma unroll
        for (int rg = 0; rg < 4; ++rg) {
            float x2 = x2g[mt * BM + wm * 64 + mf * 16 + lh * 4 + rg];
#pragma unroll
            for (int nf = 0; nf < 5; ++nf) {
                float d2 = x2 + y2v[nf] - 2.f * acc[mf][nf][rg];
                float d  = sqrtf(fmaxf(d2, 0.f));
                mloc[nf] = fminf(mloc[nf], d);
                CH(wm, lh * 4 + rg, wn * 80 + nf * 16 + l15) = d;
            }
        }
        __syncthreads();   // CH slab-set complete (K-loop readers long done)

        // coalesced writeout: 32 rows x 160 cols = 1280 f32x4, 5/thread.
        // run r: p16 = r>>1 (proto), slab = r&1 (64-row stride); 160 floats
        // (16 s-rows x 10 k) contiguous & 16B-aligned for fixed (b, p).
#pragma unroll
        for (int i = 0; i < 5; ++i) {
            int fid = i * 256 + tid;
            int r   = fid / 40;
            int q   = fid - r * 40;
            int p16 = r >> 1;
            int slab= r & 1;
            int e   = 4 * q;
            int p   = nt * 16 + p16;
            if (p < P_) {
                f32x4 v;
                v.x = CH(slab, (e + 0) / 10, p16 * 10 + (e + 0) % 10);
                v.y = CH(slab, (e + 1) / 10, p16 * 10 + (e + 1) % 10);
                v.z = CH(slab, (e + 2) / 10, p16 * 10 + (e + 2) % 10);
                v.w = CH(slab, (e + 3) / 10, p16 * 10 + (e + 3) % 10);
                int s_start = s0 + slab * 64 + mf * 16;
                size_t base = ((size_t)(b * P_ + p) * S_ + s_start) * 10 + e;
                __builtin_nontemporal_store(v, (f32x4*)(dist + base));
            }
        }
        __syncthreads();   // writeout done before next mf overwrites CH
    }
#undef CH

    // fused s-min: shfl over lh completes each wave's 64 rows; red[] combines
    // the 2 wm bands per column band.
#pragma unroll
    for (int nf = 0; nf < 5; ++nf) {
        mloc[nf] = fminf(mloc[nf], __shfl_xor(mloc[nf], 16));
        mloc[nf] = fminf(mloc[nf], __shfl_xor(mloc[nf], 32));
    }
    if (lane < 16) {
#pragma unroll
        for (int nf = 0; nf < 5; ++nf) red[wv][nf * 16 + lane] = mloc[nf];
    }
    __syncthreads();
    if (tid < BN) {
        int wn_ = tid / 80;
        int cl  = tid - wn_ * 80;
        float v = fminf(red[0 * 2 + wn_][cl], red[1 * 2 + wn_][cl]);
        ws_min[(size_t)mt * NBPAD + nt * BN + tid] = v;
    }
}

// ---------------------------------------------------------------------------
// Final: min over 4 m-subtiles, mean over k -> pd; then FC. One block per b.
__global__ __launch_bounds__(256) void mean_fc(const float* __restrict__ ws_min,
                                               const float* __restrict__ fcw,
                                               float* __restrict__ pd,
                                               float* __restrict__ cls) {
    const int b = blockIdx.x;
    const int t = threadIdx.x;
    __shared__ float pds[P_];
    if (t < P_) {
        float sum = 0.f;
#pragma unroll
        for (int k = 0; k < K_; ++k) {
            float m = 3.4e38f;
#pragma unroll
            for (int st = 0; st < 4; ++st)
                m = fminf(m, ws_min[(size_t)(b * 4 + st) * NBPAD + t * K_ + k]);
            sum += m;
        }
        float v = sum * (1.0f / K_);
        pd[b * P_ + t] = v;
        pds[t] = v;
    }
    __syncthreads();
    if (t < C_) {
        float s = 0.f;
        for (int p = 0; p < P_; ++p) s += pds[p] * fcw[t * P_ + p];
        cls[b * C_ + t] = s;
    }
}

// ---------------------------------------------------------------------------
// Fallback path (no-workspace): round-3 fused kernel + min_mean + fc.
#define FBM 128
#define FBN 80
#define FBKS 64
#define FNST 16
__device__ __forceinline__ int swzf(int row, int kbyte) {
    return (row * (FBKS * 2) + kbyte) ^ ((row & 7) << 4);
}
__global__ __launch_bounds__(256) void dist_mfma_fb(const float* __restrict__ emb,
                                                    const float* __restrict__ proto,
                                                    float* __restrict__ dist) {
    __shared__ short As[FBM * FBKS];
    __shared__ short Bs[FBN * FBKS];
    __shared__ float x2s[FBM];
    __shared__ float y2s[FBN];

    const int tid  = threadIdx.x;
    const int lane = tid & 63;
    const int wv   = tid >> 6;
    const int l15  = lane & 15;
    const int lh   = lane >> 4;

    const int id = blockIdx.x;
    const int sw = (id & 7) * (6400 / 8) + (id >> 3);
    const int nt = sw % 25;
    const int mt = sw / 25;

    const float* Ab = emb + (size_t)mt * FBM * E_ + (size_t)(tid >> 4) * E_ + (tid & 15) * 4;
    const float* Bb = proto + (size_t)nt * FBN * E_ + (size_t)(tid >> 4) * E_ + (tid & 15) * 4;

    f32x4 acc[2][5];
#pragma unroll
    for (int i = 0; i < 2; ++i)
#pragma unroll
        for (int j = 0; j < 5; ++j) acc[i][j] = (f32x4){0.f, 0.f, 0.f, 0.f};

    float x2p[8], y2p[5];
#pragma unroll
    for (int i = 0; i < 8; ++i) x2p[i] = 0.f;
#pragma unroll
    for (int i = 0; i < 5; ++i) y2p[i] = 0.f;

    float4 pa[8], pb[5];
#pragma unroll
    for (int i = 0; i < 8; ++i) pa[i] = *(const float4*)(Ab + (size_t)i * 16 * E_);
#pragma unroll
    for (int i = 0; i < 5; ++i) pb[i] = *(const float4*)(Bb + (size_t)i * 16 * E_);

    for (int t = 0; t < FNST; ++t) {
        ushort4 ca[8];
#pragma unroll
        for (int i = 0; i < 8; ++i) {
            float4 v = pa[i];
            x2p[i] += v.x * v.x + v.y * v.y + v.z * v.z + v.w * v.w;
            ca[i] = (ushort4){ f2bf(v.x), f2bf(v.y), f2bf(v.z), f2bf(v.w) };
        }
        ushort4 cb[5];
#pragma unroll
        for (int i = 0; i < 5; ++i) {
            float4 v = pb[i];
            y2p[i] += v.x * v.x + v.y * v.y + v.z * v.z + v.w * v.w;
            cb[i] = (ushort4){ f2bf(v.x), f2bf(v.y), f2bf(v.z), f2bf(v.w) };
        }
        __syncthreads();
#pragma unroll
        for (int i = 0; i < 8; ++i) {
            int idx = i * 256 + tid;
            *(ushort4*)((char*)As + swzf(idx >> 4, (idx & 15) * 8)) = ca[i];
        }
#pragma unroll
        for (int i = 0; i < 5; ++i) {
            int idx = i * 256 + tid;
            *(ushort4*)((char*)Bs + swzf(idx >> 4, (idx & 15) * 8)) = cb[i];
        }
        __syncthreads();
        if (t + 1 < FNST) {
            const float* An = Ab + (size_t)(t + 1) * FBKS;
            const float* Bn = Bb + (size_t)(t + 1) * FBKS;
#pragma unroll
            for (int i = 0; i < 8; ++i) pa[i] = *(const float4*)(An + (size_t)i * 16 * E_);
#pragma unroll
            for (int i = 0; i < 5; ++i) pb[i] = *(const float4*)(Bn + (size_t)i * 16 * E_);
        }
#pragma unroll
        for (int kk = 0; kk < 2; ++kk) {
            const int kbyte = kk * 64 + lh * 16;
            short8 af[2];
#pragma unroll
            for (int mf = 0; mf < 2; ++mf)
                af[mf] = *(const short8*)((const char*)As + swzf(wv * 32 + mf * 16 + l15, kbyte));
            short8 bfr[5];
#pragma unroll
            for (int nf = 0; nf < 5; ++nf)
                bfr[nf] = *(const short8*)((const char*)Bs + swzf(nf * 16 + l15, kbyte));
#pragma unroll
            for (int mf = 0; mf < 2; ++mf)
#pragma unroll
                for (int nf = 0; nf < 5; ++nf)
                    acc[mf][nf] = __builtin_amdgcn_mfma_f32_16x16x32_bf16(
                        af[mf], bfr[nf], acc[mf][nf], 0, 0, 0);
        }
    }

#pragma unroll
    for (int i = 0; i < 8; ++i) {
        float v = x2p[i];
        v += __shfl_xor(v, 1); v += __shfl_xor(v, 2);
        v += __shfl_xor(v, 4); v += __shfl_xor(v, 8);
        if (l15 == 0) x2s[16 * i + (tid >> 4)] = v;
    }
#pragma unroll
    for (int i = 0; i < 5; ++i) {
        float v = y2p[i];
        v += __shfl_xor(v, 1); v += __shfl_xor(v, 2);
        v += __shfl_xor(v, 4); v += __shfl_xor(v, 8);
        if (l15 == 0) y2s[16 * i + (tid >> 4)] = v;
    }
    __syncthreads();

#pragma unroll
    for (int mf = 0; mf < 2; ++mf) {
#pragma unroll
        for (int nf = 0; nf < 5; ++nf) {
#pragma unroll
            for (int rg = 0; rg < 4; ++rg) {
                int ml = wv * 32 + mf * 16 + lh * 4 + rg;
                int nl = nf * 16 + l15;
                int m = mt * FBM + ml;
                int n = nt * FBN + nl;
                int b = m >> 9;
                int s = m & (S_ - 1);
                int p = n / K_;
                int k = n - p * K_;
                float d2 = x2s[ml] + y2s[nl] - 2.f * acc[mf][nf][rg];
                dist[(((size_t)b * P_ + p) * S_ + s) * K_ + k] = sqrtf(fmaxf(d2, 0.f));
            }
        }
    }
}

__global__ __launch_bounds__(256) void min_mean(const float* __restrict__ dist,
                                                float* __restrict__ pd) {
    const int p = blockIdx.x;
    const int b = blockIdx.y;
    const float* dp = dist + ((size_t)b * P_ + p) * (size_t)(S_ * K_);
    const int tid = threadIdx.x;

    const float4* base = (const float4*)(dp + (size_t)tid * 20);
    float4 q0 = base[0], q1 = base[1], q2 = base[2], q3 = base[3], q4 = base[4];

    float mn[K_];
    mn[0] = fminf(q0.x, q2.z); mn[1] = fminf(q0.y, q2.w);
    mn[2] = fminf(q0.z, q3.x); mn[3] = fminf(q0.w, q3.y);
    mn[4] = fminf(q1.x, q3.z); mn[5] = fminf(q1.y, q3.w);
    mn[6] = fminf(q1.z, q4.x); mn[7] = fminf(q1.w, q4.y);
    mn[8] = fminf(q2.x, q4.z); mn[9] = fminf(q2.y, q4.w);

#pragma unroll
    for (int k = 0; k < K_; ++k) {
#pragma unroll
        for (int off = 32; off > 0; off >>= 1)
            mn[k] = fminf(mn[k], __shfl_xor(mn[k], off));
    }

    __shared__ float red[4][K_];
    if ((tid & 63) == 0) {
#pragma unroll
        for (int k = 0; k < K_; ++k) red[tid >> 6][k] = mn[k];
    }
    __syncthreads();
    if (tid == 0) {
        float sum = 0.f;
#pragma unroll
        for (int k = 0; k < K_; ++k)
            sum += fminf(fminf(red[0][k], red[1][k]), fminf(red[2][k], red[3][k]));
        pd[b * P_ + p] = sum * (1.0f / K_);
    }
}

__global__ void fc_kernel(const float* __restrict__ pd, const float* __restrict__ fc,
                          float* __restrict__ cls) {
    int tid = threadIdx.x;
    if (tid < B_ * C_) {
        int b = tid / C_;
        int c = tid % C_;
        float s = 0.f;
        for (int p = 0; p < P_; ++p) s += pd[b * P_ + p] * fc[c * P_ + p];
        cls[b * C_ + c] = s;
    }
}

extern "C" void kernel_launch(void* const* d_in, const int* in_sizes, int n_in,
                              void* d_out, int out_size, void* d_ws, size_t ws_size,
                              hipStream_t stream) {
    const float* emb   = (const float*)d_in[0];   // [64,512,1024]
    const float* proto = (const float*)d_in[1];   // [200,10,1024]
    const float* fc    = (const float*)d_in[2];   // [3,200]
    float* out = (float*)d_out;

    float* pd   = out;                                                // [64,200]
    float* dist = out + (size_t)B_ * P_;                              // [64,200,512,10]
    float* cls  = out + (size_t)B_ * P_ + (size_t)B_ * P_ * S_ * K_;  // [64,3]

    const size_t bf_bytes  = (size_t)NROWS_P * E_ * 2;                // 71,368,704
    const size_t xy2_bytes = (size_t)NROWS_P * 4;                     // 139,392
    const size_t min_bytes = (size_t)NMT * NBPAD * 4;                 // 2,129,920
    const size_t ws_need   = bf_bytes + xy2_bytes + min_bytes;

    if (ws_size >= ws_need) {
        unsigned short* bf = (unsigned short*)d_ws;
        float* xy2    = (float*)((char*)d_ws + bf_bytes);
        float* ws_min = (float*)((char*)d_ws + bf_bytes + xy2_bytes);
        preconvert<<<NROWS_P / 4, 256, 0, stream>>>(emb, proto, bf, xy2);
        dist_gemm_bf<<<NMT * NNT, 256, 0, stream>>>(bf, bf + (size_t)NROWS_A * E_,
                                                    xy2, xy2 + NROWS_A, dist, ws_min);
        mean_fc<<<B_, 256, 0, stream>>>(ws_min, fc, pd, cls);
    } else {
        dist_mfma_fb<<<6400, 256, 0, stream>>>(emb, proto, dist);
        min_mean<<<dim3(P_, B_), 256, 0, stream>>>(dist, pd);
        fc_kernel<<<1, 256, 0, stream>>>(pd, fc, cls);
    }
}

// Round 18
// 235.913 us; speedup vs baseline: 1.0620x; 1.0620x over previous
//
#include <hip/hip_runtime.h>
#include <hip/hip_bf16.h>

#define B_ 64
#define S_ 512
#define E_ 1024
#define P_ 200
#define K_ 10
#define C_ 3

#define BM 256
#define BN 160                 // 16 protos
#define BKS 64                 // K elements per LDS stage
#define NSTAGE (E_ / BKS)      // 16
#define NROWS_A (B_ * S_)      // 32768
#define NROWS_B (P_ * K_)      // 2000
#define NMT 128                // m-tiles (32768/256)
#define NNT 13                 // n-tiles (2080/160)
#define NBPAD (NNT * BN)       // 2080
#define NROWS_P (NROWS_A + NBPAD)  // 34848

typedef __attribute__((ext_vector_type(8))) short short8;
typedef __attribute__((ext_vector_type(4))) float f32x4;

__device__ __forceinline__ float bf2f(unsigned short u) {
    unsigned int x = ((unsigned int)u) << 16;
    return __uint_as_float(x);
}
__device__ __forceinline__ unsigned short f2bf(float f) {
    __hip_bfloat16 h = __float2bfloat16(f);
    unsigned short u;
    __builtin_memcpy(&u, &h, 2);
    return u;
}

// Read-side swizzle: row-major [row][64] bf16 (row stride 128 B); logical 16B
// chunk kbyte>>4 lives at physical slot (kbyte>>4)^(row&7). Involution with the
// pre-swizzled staging SOURCE column (rule #21 / m173). Verified conflict-free
// for the 16x16 fragment read pattern (r4/r5: SQ_LDS_BANK_CONFLICT = 0).
__device__ __forceinline__ int swz(int row, int kbyte) {
    return (row * (BKS * 2) + kbyte) ^ ((row & 7) << 4);
}

#define GLDS16(gsrc, ldst)                                                              \
    __builtin_amdgcn_global_load_lds((const __attribute__((address_space(1))) unsigned int*)(gsrc), \
                                     (__attribute__((address_space(3))) unsigned int*)(ldst), 16, 0, 0)

// ---------------------------------------------------------------------------
// Pass 1: f32 -> bf16 for emb (rows 0..32767), proto (rows 32768..34767),
// zero pad (34768..34847); per-row |.|^2 of the rounded values.
__global__ __launch_bounds__(256) void preconvert(const float* __restrict__ emb,
                                                  const float* __restrict__ proto,
                                                  unsigned short* __restrict__ bf,
                                                  float* __restrict__ xy2) {
    const int row  = blockIdx.x * 4 + (threadIdx.x >> 6);
    const int lane = threadIdx.x & 63;
    unsigned short* dst = bf + (size_t)row * E_;

    if (row >= NROWS_A + NROWS_B) {
        ushort4 z = {0, 0, 0, 0};
#pragma unroll
        for (int p = 0; p < 4; ++p) *(ushort4*)(dst + p * 256 + lane * 4) = z;
        if (lane == 0) xy2[row] = 0.f;
        return;
    }
    const float* src = (row < NROWS_A) ? emb + (size_t)row * E_
                                       : proto + (size_t)(row - NROWS_A) * E_;
    float s = 0.f;
#pragma unroll
    for (int p = 0; p < 4; ++p) {
        float4 v = *(const float4*)(src + p * 256 + lane * 4);
        ushort4 h = { f2bf(v.x), f2bf(v.y), f2bf(v.z), f2bf(v.w) };
        float a = bf2f(h.x), b = bf2f(h.y), c = bf2f(h.z), d = bf2f(h.w);
        s += a * a + b * b + c * c + d * d;
        *(ushort4*)(dst + p * 256 + lane * 4) = h;
    }
#pragma unroll
    for (int off = 32; off > 0; off >>= 1) s += __shfl_xor(s, off);
    if (lane == 0) xy2[row] = s;
}

// ---------------------------------------------------------------------------
// Pass 2: bf16 GEMM, BM=256 x BN=160, 512 threads / 8 waves as 4m x 2n.
// Each wave: 64 rows x 80 cols = 4x5 16x16 frags -> 9 ds_read_b128 per kk for
// 20 MFMA (0.45 reads/MFMA) -- the confirmed LDS-bytes-per-FLOP optimum of
// this structure family (best @ 236 us; r13/r14/r15/r17 variants all
// regressed). BKS=64 dbuf (104 KB LDS, 1 block/CU, 2 waves/SIMD), r4 schedule.
__global__ __launch_bounds__(512) void dist_gemm_bf(const unsigned short* __restrict__ Abf,
                                                    const unsigned short* __restrict__ Bbf,
                                                    const float* __restrict__ x2g,
                                                    const float* __restrict__ y2g,
                                                    float* __restrict__ dist,
                                                    float* __restrict__ ws_min) {
    __shared__ __align__(16) unsigned char smem[106496]; // As 2x32KB | Bs 2x20KB ; CH aliases
    __shared__ float red[8][80];                         // 2.5 KB

    unsigned short* AsBase = (unsigned short*)smem;                       // [2][BM*BKS]
    unsigned short* BsBase = (unsigned short*)(smem + 2 * BM * BKS * 2);  // [2][BN*BKS]
    float* Ch = (float*)smem;                                             // [4][16][162] = 41.5 KB

    const int tid  = threadIdx.x;
    const int lane = tid & 63;
    const int wv   = tid >> 6;      // 0..7
    const int wm   = wv >> 1;       // 0..3  (64-row band)
    const int wn   = wv & 1;        // 0..1  (80-col band)
    const int l15  = lane & 15;
    const int lh   = lane >> 4;

    // XCD-aware swizzle (1664 % 8 == 0): each XCD gets 16 consecutive m-tiles
    // x all 13 n-tiles.
    const int id = blockIdx.x;
    const int sw = (id & 7) * (1664 / 8) + (id >> 3);
    const int nt = sw % NNT;
    const int mt = sw / NNT;

    // Staging. A: 2048 chunks, 4/thread. B: 1280 chunks, 2/thread + waves 0-3
    // take chunks 1024..1279. LDS dest linear; swizzle via source col c^(r&7).
    const unsigned short* aSrc[4];
    unsigned lOffA[4];
#pragma unroll
    for (int i = 0; i < 4; ++i) {
        int idx = i * 512 + tid;
        int r = idx >> 3, c = idx & 7;
        aSrc[i]  = Abf + (size_t)(mt * BM + r) * E_ + (c ^ (r & 7)) * 8;
        lOffA[i] = (unsigned)(i * 512 + wv * 64) * 8;
    }
    const unsigned short* bSrc[3];
    unsigned lOffB[3];
#pragma unroll
    for (int i = 0; i < 2; ++i) {
        int idx = i * 512 + tid;
        int r = idx >> 3, c = idx & 7;
        bSrc[i]  = Bbf + (size_t)(nt * BN + r) * E_ + (c ^ (r & 7)) * 8;
        lOffB[i] = (unsigned)(i * 512 + wv * 64) * 8;
    }
    {
        int idx = 1024 + wv * 64 + lane;   // chunks 1024..1279 (waves 0..3)
        int r = idx >> 3, c = idx & 7;
        bSrc[2]  = Bbf + (size_t)(nt * BN + (r < BN ? r : 0)) * E_ + (c ^ (r & 7)) * 8;
        lOffB[2] = (unsigned)(1024 + wv * 64) * 8;
    }

    f32x4 acc[4][5];
#pragma unroll
    for (int i = 0; i < 4; ++i)
#pragma unroll
        for (int j = 0; j < 5; ++j) acc[i][j] = (f32x4){0.f, 0.f, 0.f, 0.f};

#define ISSUE(tt, bb)                                                          \
    do {                                                                       \
        const size_t ko_ = (size_t)(tt) * BKS;                                 \
        unsigned short* Asb_ = AsBase + (bb) * (BM * BKS);                     \
        unsigned short* Bsb_ = BsBase + (bb) * (BN * BKS);                     \
        _Pragma("unroll")                                                      \
        for (int i_ = 0; i_ < 4; ++i_) GLDS16(aSrc[i_] + ko_, Asb_ + lOffA[i_]); \
        _Pragma("unroll")                                                      \
        for (int i_ = 0; i_ < 2; ++i_) GLDS16(bSrc[i_] + ko_, Bsb_ + lOffB[i_]); \
        if (wv < 4) GLDS16(bSrc[2] + ko_, Bsb_ + lOffB[2]);                    \
    } while (0)

#define COMPUTE(bb)                                                            \
    do {                                                                       \
        const char* Ab_ = (const char*)(AsBase + (bb) * (BM * BKS));           \
        const char* Bb_ = (const char*)(BsBase + (bb) * (BN * BKS));           \
        _Pragma("unroll")                                                      \
        for (int kk = 0; kk < 2; ++kk) {                                       \
            const int kbyte = kk * 64 + lh * 16;                               \
            short8 af[4];                                                      \
            _Pragma("unroll")                                                  \
            for (int mf = 0; mf < 4; ++mf)                                     \
                af[mf] = *(const short8*)(Ab_ + swz(wm * 64 + mf * 16 + l15, kbyte)); \
            short8 bfr[5];                                                     \
            _Pragma("unroll")                                                  \
            for (int nf = 0; nf < 5; ++nf)                                     \
                bfr[nf] = *(const short8*)(Bb_ + swz(wn * 80 + nf * 16 + l15, kbyte)); \
            _Pragma("unroll")                                                  \
            for (int mf = 0; mf < 4; ++mf)                                     \
                _Pragma("unroll")                                              \
                for (int nf = 0; nf < 5; ++nf)                                 \
                    acc[mf][nf] = __builtin_amdgcn_mfma_f32_16x16x32_bf16(     \
                        af[mf], bfr[nf], acc[mf][nf], 0, 0, 0);                \
        }                                                                      \
    } while (0)

    ISSUE(0, 0);
    __syncthreads();

    int buf = 0;
    for (int t = 0; t < NSTAGE; ++t) {
        if (t + 1 < NSTAGE) ISSUE(t + 1, buf ^ 1);
        COMPUTE(buf);
        __syncthreads();
        buf ^= 1;
    }
#undef ISSUE
#undef COMPUTE

    // ----- Epilogue -----
    // C/D layout: col = lane&15, row = (lane>>4)*4 + reg.
    const int b  = mt >> 1;            // BM=256: two m-tiles per b
    const int s0 = (mt & 1) * 256;

    float y2v[5];
#pragma unroll
    for (int nf = 0; nf < 5; ++nf) y2v[nf] = y2g[nt * BN + wn * 80 + nf * 16 + l15];

    float mloc[5];
#pragma unroll
    for (int nf = 0; nf < 5; ++nf) mloc[nf] = 3.4e38f;

#define CH(slab, row, col) Ch[(((slab) * 16) + (row)) * 162 + (col)]

#pragma unroll
    for (int mf = 0; mf < 4; ++mf) {   // rows wm*64 + mf*16 + 0..15 (4 slabs x 16 rows)
#pragma unroll
        for (int rg = 0; rg < 4; ++rg) {
            float x2 = x2g[mt * BM + wm * 64 + mf * 16 + lh * 4 + rg];
#pragma unroll
            for (int nf = 0; nf < 5; ++nf) {
                float d2 = x2 + y2v[nf] - 2.f * acc[mf][nf][rg];
                float d  = sqrtf(fmaxf(d2, 0.f));
                mloc[nf] = fminf(mloc[nf], d);
                CH(wm, lh * 4 + rg, wn * 80 + nf * 16 + l15) = d;
            }
        }
        __syncthreads();   // CH slab-set complete (K-loop readers long done)

        // coalesced writeout: 64 rows x 160 cols = 2560 f32x4, 5/thread.
        // run r: p16 = r>>2 (proto), slab = r&3 (64-row stride); 160 floats
        // (16 s-rows x 10 k) contiguous & 16B-aligned for fixed (b, p).
#pragma unroll
        for (int i = 0; i < 5; ++i) {
            int fid = i * 512 + tid;
            int r   = fid / 40;
            int q   = fid - r * 40;
            int p16 = r >> 2;
            int slab= r & 3;
            int e   = 4 * q;
            int p   = nt * 16 + p16;
            if (p < P_) {
                f32x4 v;
                v.x = CH(slab, (e + 0) / 10, p16 * 10 + (e + 0) % 10);
                v.y = CH(slab, (e + 1) / 10, p16 * 10 + (e + 1) % 10);
                v.z = CH(slab, (e + 2) / 10, p16 * 10 + (e + 2) % 10);
                v.w = CH(slab, (e + 3) / 10, p16 * 10 + (e + 3) % 10);
                int s_start = s0 + slab * 64 + mf * 16;
                size_t base = ((size_t)(b * P_ + p) * S_ + s_start) * 10 + e;
                __builtin_nontemporal_store(v, (f32x4*)(dist + base));
            }
        }
        __syncthreads();   // writeout done before next mf overwrites CH
    }
#undef CH

    // fused s-min: per-lane min covered rows {wm*64 + mf*16 + lh*4 + rg};
    // shfl over lh completes the wave's 64 rows; red[] combines the 4 wm bands.
#pragma unroll
    for (int nf = 0; nf < 5; ++nf) {
        mloc[nf] = fminf(mloc[nf], __shfl_xor(mloc[nf], 16));
        mloc[nf] = fminf(mloc[nf], __shfl_xor(mloc[nf], 32));
    }
    if (lane < 16) {
#pragma unroll
        for (int nf = 0; nf < 5; ++nf) red[wv][nf * 16 + lane] = mloc[nf];
    }
    __syncthreads();
    if (tid < BN) {
        int wn_ = tid / 80;
        int cl  = tid - wn_ * 80;
        float v = fminf(fminf(red[0 * 2 + wn_][cl], red[1 * 2 + wn_][cl]),
                        fminf(red[2 * 2 + wn_][cl], red[3 * 2 + wn_][cl]));
        ws_min[(size_t)mt * NBPAD + nt * BN + tid] = v;
    }
}

// ---------------------------------------------------------------------------
// Final: min over 2 m-subtiles, mean over k -> pd; then FC. One block per b.
__global__ __launch_bounds__(256) void mean_fc(const float* __restrict__ ws_min,
                                               const float* __restrict__ fcw,
                                               float* __restrict__ pd,
                                               float* __restrict__ cls) {
    const int b = blockIdx.x;
    const int t = threadIdx.x;
    __shared__ float pds[P_];
    if (t < P_) {
        float sum = 0.f;
#pragma unroll
        for (int k = 0; k < K_; ++k) {
            float m = fminf(ws_min[(size_t)(b * 2 + 0) * NBPAD + t * K_ + k],
                            ws_min[(size_t)(b * 2 + 1) * NBPAD + t * K_ + k]);
            sum += m;
        }
        float v = sum * (1.0f / K_);
        pd[b * P_ + t] = v;
        pds[t] = v;
    }
    __syncthreads();
    if (t < C_) {
        float s = 0.f;
        for (int p = 0; p < P_; ++p) s += pds[p] * fcw[t * P_ + p];
        cls[b * C_ + t] = s;
    }
}

// ---------------------------------------------------------------------------
// Fallback path (no-workspace): round-3 fused kernel + min_mean + fc.
#define FBM 128
#define FBN 80
#define FBKS 64
#define FNST 16
__device__ __forceinline__ int swzf(int row, int kbyte) {
    return (row * (FBKS * 2) + kbyte) ^ ((row & 7) << 4);
}
__global__ __launch_bounds__(256) void dist_mfma_fb(const float* __restrict__ emb,
                                                    const float* __restrict__ proto,
                                                    float* __restrict__ dist) {
    __shared__ short As[FBM * FBKS];
    __shared__ short Bs[FBN * FBKS];
    __shared__ float x2s[FBM];
    __shared__ float y2s[FBN];

    const int tid  = threadIdx.x;
    const int lane = tid & 63;
    const int wv   = tid >> 6;
    const int l15  = lane & 15;
    const int lh   = lane >> 4;

    const int id = blockIdx.x;
    const int sw = (id & 7) * (6400 / 8) + (id >> 3);
    const int nt = sw % 25;
    const int mt = sw / 25;

    const float* Ab = emb + (size_t)mt * FBM * E_ + (size_t)(tid >> 4) * E_ + (tid & 15) * 4;
    const float* Bb = proto + (size_t)nt * FBN * E_ + (size_t)(tid >> 4) * E_ + (tid & 15) * 4;

    f32x4 acc[2][5];
#pragma unroll
    for (int i = 0; i < 2; ++i)
#pragma unroll
        for (int j = 0; j < 5; ++j) acc[i][j] = (f32x4){0.f, 0.f, 0.f, 0.f};

    float x2p[8], y2p[5];
#pragma unroll
    for (int i = 0; i < 8; ++i) x2p[i] = 0.f;
#pragma unroll
    for (int i = 0; i < 5; ++i) y2p[i] = 0.f;

    float4 pa[8], pb[5];
#pragma unroll
    for (int i = 0; i < 8; ++i) pa[i] = *(const float4*)(Ab + (size_t)i * 16 * E_);
#pragma unroll
    for (int i = 0; i < 5; ++i) pb[i] = *(const float4*)(Bb + (size_t)i * 16 * E_);

    for (int t = 0; t < FNST; ++t) {
        ushort4 ca[8];
#pragma unroll
        for (int i = 0; i < 8; ++i) {
            float4 v = pa[i];
            x2p[i] += v.x * v.x + v.y * v.y + v.z * v.z + v.w * v.w;
            ca[i] = (ushort4){ f2bf(v.x), f2bf(v.y), f2bf(v.z), f2bf(v.w) };
        }
        ushort4 cb[5];
#pragma unroll
        for (int i = 0; i < 5; ++i) {
            float4 v = pb[i];
            y2p[i] += v.x * v.x + v.y * v.y + v.z * v.z + v.w * v.w;
            cb[i] = (ushort4){ f2bf(v.x), f2bf(v.y), f2bf(v.z), f2bf(v.w) };
        }
        __syncthreads();
#pragma unroll
        for (int i = 0; i < 8; ++i) {
            int idx = i * 256 + tid;
            *(ushort4*)((char*)As + swzf(idx >> 4, (idx & 15) * 8)) = ca[i];
        }
#pragma unroll
        for (int i = 0; i < 5; ++i) {
            int idx = i * 256 + tid;
            *(ushort4*)((char*)Bs + swzf(idx >> 4, (idx & 15) * 8)) = cb[i];
        }
        __syncthreads();
        if (t + 1 < FNST) {
            const float* An = Ab + (size_t)(t + 1) * FBKS;
            const float* Bn = Bb + (size_t)(t + 1) * FBKS;
#pragma unroll
            for (int i = 0; i < 8; ++i) pa[i] = *(const float4*)(An + (size_t)i * 16 * E_);
#pragma unroll
            for (int i = 0; i < 5; ++i) pb[i] = *(const float4*)(Bn + (size_t)i * 16 * E_);
        }
#pragma unroll
        for (int kk = 0; kk < 2; ++kk) {
            const int kbyte = kk * 64 + lh * 16;
            short8 af[2];
#pragma unroll
            for (int mf = 0; mf < 2; ++mf)
                af[mf] = *(const short8*)((const char*)As + swzf(wv * 32 + mf * 16 + l15, kbyte));
            short8 bfr[5];
#pragma unroll
            for (int nf = 0; nf < 5; ++nf)
                bfr[nf] = *(const short8*)((const char*)Bs + swzf(nf * 16 + l15, kbyte));
#pragma unroll
            for (int mf = 0; mf < 2; ++mf)
#pragma unroll
                for (int nf = 0; nf < 5; ++nf)
                    acc[mf][nf] = __builtin_amdgcn_mfma_f32_16x16x32_bf16(
                        af[mf], bfr[nf], acc[mf][nf], 0, 0, 0);
        }
    }

#pragma unroll
    for (int i = 0; i < 8; ++i) {
        float v = x2p[i];
        v += __shfl_xor(v, 1); v += __shfl_xor(v, 2);
        v += __shfl_xor(v, 4); v += __shfl_xor(v, 8);
        if (l15 == 0) x2s[16 * i + (tid >> 4)] = v;
    }
#pragma unroll
    for (int i = 0; i < 5; ++i) {
        float v = y2p[i];
        v += __shfl_xor(v, 1); v += __shfl_xor(v, 2);
        v += __shfl_xor(v, 4); v += __shfl_xor(v, 8);
        if (l15 == 0) y2s[16 * i + (tid >> 4)] = v;
    }
    __syncthreads();

#pragma unroll
    for (int mf = 0; mf < 2; ++mf) {
#pragma unroll
        for (int nf = 0; nf < 5; ++nf) {
#pragma unroll
            for (int rg = 0; rg < 4; ++rg) {
                int ml = wv * 32 + mf * 16 + lh * 4 + rg;
                int nl = nf * 16 + l15;
                int m = mt * FBM + ml;
                int n = nt * FBN + nl;
                int b = m >> 9;
                int s = m & (S_ - 1);
                int p = n / K_;
                int k = n - p * K_;
                float d2 = x2s[ml] + y2s[nl] - 2.f * acc[mf][nf][rg];
                dist[(((size_t)b * P_ + p) * S_ + s) * K_ + k] = sqrtf(fmaxf(d2, 0.f));
            }
        }
    }
}

__global__ __launch_bounds__(256) void min_mean(const float* __restrict__ dist,
                                                float* __restrict__ pd) {
    const int p = blockIdx.x;
    const int b = blockIdx.y;
    const float* dp = dist + ((size_t)b * P_ + p) * (size_t)(S_ * K_);
    const int tid = threadIdx.x;

    const float4* base = (const float4*)(dp + (size_t)tid * 20);
    float4 q0 = base[0], q1 = base[1], q2 = base[2], q3 = base[3], q4 = base[4];

    float mn[K_];
    mn[0] = fminf(q0.x, q2.z); mn[1] = fminf(q0.y, q2.w);
    mn[2] = fminf(q0.z, q3.x); mn[3] = fminf(q0.w, q3.y);
    mn[4] = fminf(q1.x, q3.z); mn[5] = fminf(q1.y, q3.w);
    mn[6] = fminf(q1.z, q4.x); mn[7] = fminf(q1.w, q4.y);
    mn[8] = fminf(q2.x, q4.z); mn[9] = fminf(q2.y, q4.w);

#pragma unroll
    for (int k = 0; k < K_; ++k) {
#pragma unroll
        for (int off = 32; off > 0; off >>= 1)
            mn[k] = fminf(mn[k], __shfl_xor(mn[k], off));
    }

    __shared__ float red[4][K_];
    if ((tid & 63) == 0) {
#pragma unroll
        for (int k = 0; k < K_; ++k) red[tid >> 6][k] = mn[k];
    }
    __syncthreads();
    if (tid == 0) {
        float sum = 0.f;
#pragma unroll
        for (int k = 0; k < K_; ++k)
            sum += fminf(fminf(red[0][k], red[1][k]), fminf(red[2][k], red[3][k]));
        pd[b * P_ + p] = sum * (1.0f / K_);
    }
}

__global__ void fc_kernel(const float* __restrict__ pd, const float* __restrict__ fc,
                          float* __restrict__ cls) {
    int tid = threadIdx.x;
    if (tid < B_ * C_) {
        int b = tid / C_;
        int c = tid % C_;
        float s = 0.f;
        for (int p = 0; p < P_; ++p) s += pd[b * P_ + p] * fc[c * P_ + p];
        cls[b * C_ + c] = s;
    }
}

extern "C" void kernel_launch(void* const* d_in, const int* in_sizes, int n_in,
                              void* d_out, int out_size, void* d_ws, size_t ws_size,
                              hipStream_t stream) {
    const float* emb   = (const float*)d_in[0];   // [64,512,1024]
    const float* proto = (const float*)d_in[1];   // [200,10,1024]
    const float* fc    = (const float*)d_in[2];   // [3,200]
    float* out = (float*)d_out;

    float* pd   = out;                                                // [64,200]
    float* dist = out + (size_t)B_ * P_;                              // [64,200,512,10]
    float* cls  = out + (size_t)B_ * P_ + (size_t)B_ * P_ * S_ * K_;  // [64,3]

    const size_t bf_bytes  = (size_t)NROWS_P * E_ * 2;                // 71,368,704
    const size_t xy2_bytes = (size_t)NROWS_P * 4;                     // 139,392
    const size_t min_bytes = (size_t)NMT * NBPAD * 4;                 // 1,064,960
    const size_t ws_need   = bf_bytes + xy2_bytes + min_bytes;

    if (ws_size >= ws_need) {
        unsigned short* bf = (unsigned short*)d_ws;
        float* xy2    = (float*)((char*)d_ws + bf_bytes);
        float* ws_min = (float*)((char*)d_ws + bf_bytes + xy2_bytes);
        preconvert<<<NROWS_P / 4, 256, 0, stream>>>(emb, proto, bf, xy2);
        dist_gemm_bf<<<NMT * NNT, 512, 0, stream>>>(bf, bf + (size_t)NROWS_A * E_,
                                                    xy2, xy2 + NROWS_A, dist, ws_min);
        mean_fc<<<B_, 256, 0, stream>>>(ws_min, fc, pd, cls);
    } else {
        dist_mfma_fb<<<6400, 256, 0, stream>>>(emb, proto, dist);
        min_mean<<<dim3(P_, B_), 256, 0, stream>>>(dist, pd);
        fc_kernel<<<1, 256, 0, stream>>>(pd, fc, cls);
    }
}